// Round 9
// baseline (46.317 us; speedup 1.0000x reference)
//
#include <hip/hip_runtime.h>

typedef float f32x4 __attribute__((ext_vector_type(4)));

// DPP controls: 16-lane group reduction = quad_perm xor1, xor2, row_ror:4, row_ror:8
#define DPP_X1 0xB1   // quad_perm [1,0,3,2]
#define DPP_X2 0x4E   // quad_perm [2,3,0,1]
#define DPP_R4 0x124  // row_ror:4
#define DPP_R8 0x128  // row_ror:8

template <int CTRL>
__device__ __forceinline__ float dpp_mv(float v) {
    return __int_as_float(__builtin_amdgcn_update_dpp(0, __float_as_int(v), CTRL, 0xF, 0xF, true));
}
template <int CTRL>
__device__ __forceinline__ double dpp_mv64(double v) {
    unsigned long long u = __double_as_longlong(v);
    int lo = __builtin_amdgcn_update_dpp(0, (int)(unsigned)(u & 0xFFFFFFFFull), CTRL, 0xF, 0xF, true);
    int hi = __builtin_amdgcn_update_dpp(0, (int)(unsigned)(u >> 32), CTRL, 0xF, 0xF, true);
    return __longlong_as_double(((unsigned long long)(unsigned)hi << 32) | (unsigned)lo);
}

// Exact floor(log2(x)) for x > 0, including denormals (block maxima only).
__device__ __forceinline__ int flog2_exact(float x) {
    unsigned b = __float_as_uint(x);
    int e = (int)((b >> 23) & 0xFFu);
    if (e == 0) {
        unsigned m = b & 0x7FFFFFu;
        return 31 - __clz(m) - 149;
    }
    return e - 127;
}

__global__ __launch_bounds__(256) void mxq_kernel(const f32x4* __restrict__ x,
                                                  f32x4* __restrict__ y,
                                                  int ntask) {  // task = 4 blocks = 512 elems
    const int lane = threadIdx.x & 63;
    const int wid  = blockIdx.x * (blockDim.x >> 6) + (threadIdx.x >> 6);
    if (wid >= ntask) return;            // one task per wave: maximal wave churn

    const size_t base = (size_t)wid * 128 + (lane >> 4) * 32 + (lane & 15);
    // Nontemporal loads: stream input past MALL so the output stream can own it.
    const f32x4 v0 = __builtin_nontemporal_load(&x[base]);
    const f32x4 v1 = __builtin_nontemporal_load(&x[base + 16]);
    float a[8] = {v0.x, v0.y, v0.z, v0.w, v1.x, v1.y, v1.z, v1.w};
    double ad[8];

    // ---- one-pass fp64 stats; single cvt per element, abs via modifier ----
    double s = 0.0, s2 = 0.0;
    #pragma unroll
    for (int i = 0; i < 8; ++i) {
        ad[i] = (double)a[i];
        s += fabs(ad[i]);                 // add_f64 with |src| modifier
        s2 = fma(ad[i], ad[i], s2);       // square is sign-free, exact
    }
    s += dpp_mv64<DPP_X1>(s);  s2 += dpp_mv64<DPP_X1>(s2);
    s += dpp_mv64<DPP_X2>(s);  s2 += dpp_mv64<DPP_X2>(s2);
    s += dpp_mv64<DPP_R4>(s);  s2 += dpp_mv64<DPP_R4>(s2);
    s += dpp_mv64<DPP_R8>(s);  s2 += dpp_mv64<DPP_R8>(s2);

    const double mean = s * (1.0 / 128.0);
    double var = fma(mean, -mean, s2 * (1.0 / 128.0));
    var = var < 0.0 ? 0.0 : var;
    const double thr = 2.0 * sqrt(var);   // |a-mean| > 2*sigma  <=> outlier

    // ---- classify + per-path maxima (2 f64 ops/elem: sub, cmp|.|) ----
    bool o[8];
    float mi = 0.0f, mov = 0.0f;
    #pragma unroll
    for (int i = 0; i < 8; ++i) {
        o[i] = fabs(ad[i] - mean) > thr;
        float zi = o[i] ? 0.0f : a[i];
        float zo = o[i] ? a[i] : 0.0f;
        mi  = fmaxf(mi,  fabsf(zi));
        mov = fmaxf(mov, fabsf(zo));
    }
    mi = fmaxf(mi, dpp_mv<DPP_X1>(mi));  mov = fmaxf(mov, dpp_mv<DPP_X1>(mov));
    mi = fmaxf(mi, dpp_mv<DPP_X2>(mi));  mov = fmaxf(mov, dpp_mv<DPP_X2>(mov));
    mi = fmaxf(mi, dpp_mv<DPP_R4>(mi));  mov = fmaxf(mov, dpp_mv<DPP_R4>(mov));
    mi = fmaxf(mi, dpp_mv<DPP_R8>(mi));  mov = fmaxf(mov, dpp_mv<DPP_R8>(mov));

    // ---- shared exponents (exact integer math) ----
    int se_in = (mi == 0.0f) ? -126 : flog2_exact(mi);       // EMAX_IN = 0
    if (se_in < -127) se_in = -20;                           // SCALE_LO
    int se_out = ((mov == 0.0f) ? -126 : (flog2_exact(mov) + se_in)) - 8;
    if (se_out < -127) se_out = -20;
    const int d    = se_in - se_out;
    const int g_in = se_in - 4;
    const int m9   = -(d + 9);                     // lower bound on g_out
    const float L_in  = ldexpf(31.0f, g_in);       // exact clamp bounds
    const float L_out = ldexpf(448.0f, -d);

    // ---- unified quantize ----
    f32x4 r0, r1;
    #pragma unroll
    for (int i = 0; i < 8; ++i) {
        int eb = (int)((__float_as_uint(a[i]) >> 23) & 0xFFu);
        int g_out = max(eb - 130, m9);     // = clamp(pe,-6..) - 3 - d  (exact)
        int g = o[i] ? g_out : g_in;
        float t2 = ldexpf(a[i], -g);
        float r  = copysignf(truncf(fabsf(t2) + 0.5f), a[i]);  // round half away
        float outv = ldexpf(r, g);
        float L = o[i] ? L_out : L_in;
        outv = __builtin_amdgcn_fmed3f(outv, -L, L);           // clamp
        if (i < 4) r0[i] = outv; else r1[i - 4] = outv;
    }

    y[base]      = r0;       // plain stores: output owns the MALL
    y[base + 16] = r1;
}

extern "C" void kernel_launch(void* const* d_in, const int* in_sizes, int n_in,
                              void* d_out, int out_size, void* d_ws, size_t ws_size,
                              hipStream_t stream) {
    const f32x4* x = (const f32x4*)d_in[0];
    f32x4* y = (f32x4*)d_out;
    int n = in_sizes[0];
    int ntask = n / 512;                 // 65536 wave-tasks (4 blocks each)
    int threads = 256;
    int waves_per_wg = threads / 64;     // 4
    int grid = (ntask + waves_per_wg - 1) / waves_per_wg;   // 16384: 1 task/wave
    mxq_kernel<<<grid, threads, 0, stream>>>(x, y, ntask);
}

// Round 10
// 43.321 us; speedup vs baseline: 1.0691x; 1.0691x over previous
//
#include <hip/hip_runtime.h>

typedef float f32x4 __attribute__((ext_vector_type(4)));

// DPP controls: 16-lane group reduction = quad_perm xor1, xor2, row_ror:4, row_ror:8
#define DPP_X1 0xB1   // quad_perm [1,0,3,2]
#define DPP_X2 0x4E   // quad_perm [2,3,0,1]
#define DPP_R4 0x124  // row_ror:4
#define DPP_R8 0x128  // row_ror:8

template <int CTRL>
__device__ __forceinline__ float dpp_mv(float v) {
    return __int_as_float(__builtin_amdgcn_update_dpp(0, __float_as_int(v), CTRL, 0xF, 0xF, true));
}
template <int CTRL>
__device__ __forceinline__ double dpp_mv64(double v) {
    unsigned long long u = __double_as_longlong(v);
    int lo = __builtin_amdgcn_update_dpp(0, (int)(unsigned)(u & 0xFFFFFFFFull), CTRL, 0xF, 0xF, true);
    int hi = __builtin_amdgcn_update_dpp(0, (int)(unsigned)(u >> 32), CTRL, 0xF, 0xF, true);
    return __longlong_as_double(((unsigned long long)(unsigned)hi << 32) | (unsigned)lo);
}

// Exact floor(log2(x)) for x > 0, including denormals (block maxima only).
__device__ __forceinline__ int flog2_exact(float x) {
    unsigned b = __float_as_uint(x);
    int e = (int)((b >> 23) & 0xFFu);
    if (e == 0) {
        unsigned m = b & 0x7FFFFFu;
        return 31 - __clz(m) - 149;
    }
    return e - 127;
}

__global__ __launch_bounds__(256) void mxq_kernel(const f32x4* __restrict__ x,
                                                  f32x4* __restrict__ y,
                                                  int ntask) {  // task = 4 blocks = 512 elems
    const int lane = threadIdx.x & 63;
    const int wid  = blockIdx.x * (blockDim.x >> 6) + (threadIdx.x >> 6);
    if (wid >= ntask) return;            // one task per wave: maximal wave churn

    const size_t base = (size_t)wid * 128 + (lane >> 4) * 32 + (lane & 15);
    const f32x4 v0 = x[base];
    const f32x4 v1 = x[base + 16];
    float a[8] = {v0.x, v0.y, v0.z, v0.w, v1.x, v1.y, v1.z, v1.w};
    float ab[8];

    // ---- FAST PATH: f32 stats over the 16-lane group (one 128-elem block) ----
    float s = 0.0f, s2 = 0.0f;
    #pragma unroll
    for (int i = 0; i < 8; ++i) {
        ab[i] = fabsf(a[i]);
        s += ab[i];
        s2 = fmaf(a[i], a[i], s2);        // sign-free square
    }
    s += dpp_mv<DPP_X1>(s);  s2 += dpp_mv<DPP_X1>(s2);
    s += dpp_mv<DPP_X2>(s);  s2 += dpp_mv<DPP_X2>(s2);
    s += dpp_mv<DPP_R4>(s);  s2 += dpp_mv<DPP_R4>(s2);
    s += dpp_mv<DPP_R8>(s);  s2 += dpp_mv<DPP_R8>(s2);

    const float meanf = s * (1.0f / 128.0f);
    const float ms2   = s2 * (1.0f / 128.0f);
    float varf = fmaf(meanf, -meanf, ms2);
    varf = varf < 0.0f ? 0.0f : varf;
    const float thrf  = 2.0f * sqrtf(varf);
    // error band: delta = 2^-13 * rms; plus cancellation guard on var itself
    const float delta = sqrtf(ms2) * 1.220703125e-4f;
    bool unc = (varf < ms2 * 2.44140625e-4f);   // var uncertain (catastrophic cancel)

    bool o[8];
    #pragma unroll
    for (int i = 0; i < 8; ++i) {
        float w = fabsf(a[i] - meanf) - thrf;
        o[i] = w > 0.0f;
        unc = unc || (fabsf(w) < delta);        // classification margin too small
    }

    // ---- SLOW PATH (rare): exact f64 redo of stats + classification ----
    if (__any((int)unc)) {
        double sd = 0.0, sd2 = 0.0;
        double ad[8];
        #pragma unroll
        for (int i = 0; i < 8; ++i) {
            ad[i] = (double)a[i];
            sd += fabs(ad[i]);
            sd2 = fma(ad[i], ad[i], sd2);
        }
        sd += dpp_mv64<DPP_X1>(sd);  sd2 += dpp_mv64<DPP_X1>(sd2);
        sd += dpp_mv64<DPP_X2>(sd);  sd2 += dpp_mv64<DPP_X2>(sd2);
        sd += dpp_mv64<DPP_R4>(sd);  sd2 += dpp_mv64<DPP_R4>(sd2);
        sd += dpp_mv64<DPP_R8>(sd);  sd2 += dpp_mv64<DPP_R8>(sd2);
        const double meand = sd * (1.0 / 128.0);
        double vard = fma(meand, -meand, sd2 * (1.0 / 128.0));
        vard = vard < 0.0 ? 0.0 : vard;
        const double thrd = 2.0 * sqrt(vard);
        #pragma unroll
        for (int i = 0; i < 8; ++i)
            o[i] = fabs((double)a[i] - meand) > thrd;
    }

    // ---- per-path maxima (exact f32) ----
    float mi = 0.0f, mov = 0.0f;
    #pragma unroll
    for (int i = 0; i < 8; ++i) {
        mi  = fmaxf(mi,  o[i] ? 0.0f : ab[i]);
        mov = fmaxf(mov, o[i] ? ab[i] : 0.0f);
    }
    mi = fmaxf(mi, dpp_mv<DPP_X1>(mi));  mov = fmaxf(mov, dpp_mv<DPP_X1>(mov));
    mi = fmaxf(mi, dpp_mv<DPP_X2>(mi));  mov = fmaxf(mov, dpp_mv<DPP_X2>(mov));
    mi = fmaxf(mi, dpp_mv<DPP_R4>(mi));  mov = fmaxf(mov, dpp_mv<DPP_R4>(mov));
    mi = fmaxf(mi, dpp_mv<DPP_R8>(mi));  mov = fmaxf(mov, dpp_mv<DPP_R8>(mov));

    // ---- shared exponents (exact integer math) ----
    int se_in = (mi == 0.0f) ? -126 : flog2_exact(mi);       // EMAX_IN = 0
    if (se_in < -127) se_in = -20;                           // SCALE_LO
    int se_out = ((mov == 0.0f) ? -126 : (flog2_exact(mov) + se_in)) - 8;
    if (se_out < -127) se_out = -20;
    const int d    = se_in - se_out;
    const int g_in = se_in - 4;
    const int m9   = -(d + 9);                     // lower bound on g_out
    const float L_in  = ldexpf(31.0f, g_in);       // exact clamp bounds
    const float L_out = ldexpf(448.0f, -d);

    // ---- unified quantize (all scalings exact powers of 2) ----
    f32x4 r0, r1;
    #pragma unroll
    for (int i = 0; i < 8; ++i) {
        int eb = (int)((__float_as_uint(a[i]) >> 23) & 0xFFu);
        int g_out = max(eb - 130, m9);     // = clamp(pe,-6..) - 3 - d  (exact)
        int g = o[i] ? g_out : g_in;
        float t2 = ldexpf(a[i], -g);
        float r  = copysignf(truncf(fabsf(t2) + 0.5f), a[i]);  // round half away
        float outv = ldexpf(r, g);
        float L = o[i] ? L_out : L_in;
        outv = __builtin_amdgcn_fmed3f(outv, -L, L);           // clamp
        if (i < 4) r0[i] = outv; else r1[i - 4] = outv;
    }

    y[base]      = r0;
    y[base + 16] = r1;
}

extern "C" void kernel_launch(void* const* d_in, const int* in_sizes, int n_in,
                              void* d_out, int out_size, void* d_ws, size_t ws_size,
                              hipStream_t stream) {
    const f32x4* x = (const f32x4*)d_in[0];
    f32x4* y = (f32x4*)d_out;
    int n = in_sizes[0];
    int ntask = n / 512;                 // 65536 wave-tasks (4 blocks each)
    int threads = 256;
    int waves_per_wg = threads / 64;     // 4
    int grid = (ntask + waves_per_wg - 1) / waves_per_wg;   // 16384: 1 task/wave
    mxq_kernel<<<grid, threads, 0, stream>>>(x, y, ntask);
}